// Round 6
// baseline (403.684 us; speedup 1.0000x reference)
//
#include <hip/hip_runtime.h>
#include <hip/hip_bf16.h>

#define B_ 256
#define T_ 32
#define F_ 128
#define H_ 128
#define NF 64
#define OH 31
#define OW 255
#define POS_TOTAL (OH*OW)      // 7905
#define N1 256
#define KT 248                 // K-slice blocks (32 pos each)
#define NSTEPS 64              // 64 steps of K=32 (4 filters x 8 pos)

typedef __attribute__((ext_vector_type(8))) short bf16x8;
typedef __attribute__((ext_vector_type(4))) float f32x4;

__device__ __forceinline__ unsigned short f2bf_rne(float f) {
    unsigned int u = __float_as_uint(f);
    u += 0x7FFFu + ((u >> 16) & 1u);
    return (unsigned short)(u >> 16);
}

// raw barrier: drain LDS ops only; vmem loads stay in flight (T4)
#define LB() do { asm volatile("s_waitcnt lgkmcnt(0)" ::: "memory"); \
                  __builtin_amdgcn_s_barrier(); } while (0)

// ---------------- K1: attention -> featL [b=256][rc=8192] ----------------
__global__ __launch_bounds__(256) void k_attn(
    const float* __restrict__ X, const float* __restrict__ W,
    const float* __restrict__ U, const float* __restrict__ V,
    float* __restrict__ featL)
{
    __shared__ float Xs[T_][F_];
    __shared__ float xw[T_][H_];
    __shared__ float xu[T_][H_];
    __shared__ float sc[T_][T_];
    __shared__ float Vs[H_];

    const int b = blockIdx.x;
    const int t = threadIdx.x;
    const float* Xb = X + (size_t)b * T_ * F_;

    for (int idx = t; idx < T_*F_; idx += 256) ((float*)Xs)[idx] = Xb[idx];
    if (t < H_) Vs[t] = V[t];
    __syncthreads();

    {
        const int h = t & 127, half = t >> 7;
        float aw[16], au[16];
        #pragma unroll
        for (int r = 0; r < 16; r++) { aw[r] = 0.f; au[r] = 0.f; }
        for (int f = 0; f < F_; f++) {
            const float wv = W[f*H_ + h];
            const float uv = U[f*H_ + h];
            #pragma unroll
            for (int r = 0; r < 16; r++) {
                const float xv = Xs[half*16 + r][f];
                aw[r] += xv * wv;
                au[r] += xv * uv;
            }
        }
        #pragma unroll
        for (int r = 0; r < 16; r++) {
            xw[half*16 + r][h] = aw[r];
            xu[half*16 + r][h] = au[r];
        }
    }
    __syncthreads();

    {
        const int i = t >> 3;
        const int j0 = (t & 7) * 4;
        float s0 = 0.f, s1 = 0.f, s2 = 0.f, s3 = 0.f;
        for (int h = 0; h < H_; h++) {
            const float xwv = xw[i][h];
            const float vv  = Vs[h];
            s0 += tanhf(xwv + xu[j0+0][h]) * vv;
            s1 += tanhf(xwv + xu[j0+1][h]) * vv;
            s2 += tanhf(xwv + xu[j0+2][h]) * vv;
            s3 += tanhf(xwv + xu[j0+3][h]) * vv;
        }
        sc[i][j0+0] = s0; sc[i][j0+1] = s1; sc[i][j0+2] = s2; sc[i][j0+3] = s3;
    }
    __syncthreads();

    if (t < T_) {
        float m = -1e30f;
        #pragma unroll
        for (int j = 0; j < T_; j++) m = fmaxf(m, sc[t][j]);
        float sum = 0.f;
        #pragma unroll
        for (int j = 0; j < T_; j++) sum += expf(sc[t][j] - m);
        const float inv = 1.f / sum;
        #pragma unroll
        for (int j = 0; j < T_; j++) {
            const float a = expf(sc[t][j] - m) * inv;
            sc[t][j] = (j == t) ? 0.f : a;
        }
    }
    __syncthreads();

    for (int idx = t; idx < T_*F_; idx += 256) {
        const int row = idx >> 7, f = idx & 127;
        float acc = 0.f;
        #pragma unroll
        for (int j = 0; j < T_; j++) acc += sc[row][j] * Xs[j][f];
        float* fr = featL + (size_t)b*8192 + row*256;
        fr[f]       = Xs[row][f];
        fr[128 + f] = acc;
    }
}

// -------- K1b: transpose featL[b][rc] -> featT[rc][b], LDS-tiled --------
__global__ __launch_bounds__(256) void k_tr(
    const float* __restrict__ src, float* __restrict__ dst)
{
    __shared__ float tile[32][33];
    const int rc0 = blockIdx.x * 32;
    const int b0  = blockIdx.y * 32;
    const int tx = threadIdx.x & 31;
    const int ty = threadIdx.x >> 5;
    #pragma unroll
    for (int r = 0; r < 32; r += 8)
        tile[ty + r][tx] = src[(size_t)(b0 + ty + r)*8192 + rc0 + tx];
    __syncthreads();
    #pragma unroll
    for (int r = 0; r < 32; r += 8)
        dst[(size_t)(rc0 + ty + r)*256 + b0 + tx] = tile[tx][ty + r];
}

// ------- K2: fused conv + MFMA GEMM1, raw barriers + 2-deep reg pipeline -------
// Grid (2 nt, 248 kt). Tile M=256 x N=128, K-slice = 32 pos, 64 steps of K=32.
__global__ __launch_bounds__(512, 2) void k_gemm1(
    const float* __restrict__ featT, const float* __restrict__ cw,
    const float* __restrict__ cb, const float* __restrict__ w1,
    float* __restrict__ partial)
{
    __shared__ unsigned short As[2][4*256*8];   // 2 x 16 KiB [blk][m][8]
    __shared__ unsigned short Ws[2][4*128*8];   // 2 x  8 KiB [blk][n][8]
    __shared__ float cwL[256];
    __shared__ float cbL[64];

    const int t  = threadIdx.x;
    const int nt = blockIdx.x;      // 0/1
    const int kt = blockIdx.y;      // 0..247
    const int nb = nt * 128;

    if (t < 256) cwL[t] = cw[t];
    if (t < 64)  cbL[t] = cb[t];

    // A staging role: row rm, 2 filters (fh)
    const int rm = t & 255;
    const int fh = t >> 8;          // 0/1
    // W staging role: col rw, 1 filter (fw)
    const int rw = t & 127;
    const int fw = t >> 7;          // 0..3
    // MFMA role: 8 waves = 4(m) x 2(n); wave tile 64x64
    const int lane = t & 63, wid = t >> 6;
    const int wm = (wid & 3) * 64;
    const int wn = (wid >> 2) * 64;
    const int fr = lane & 15, fq = lane >> 4;

    f32x4 acc[4][4];
    #pragma unroll
    for (int i = 0; i < 4; i++)
        #pragma unroll
        for (int j = 0; j < 4; j++)
            acc[i][j] = (f32x4){0.f, 0.f, 0.f, 0.f};

    float patch[4][8];
    float wvA[8], wvB[8];

    const int pb0 = kt * 4;

#define PATCH_LOADS(PB)                                                        \
    {                                                                          \
        const int pbase_ = (PB) * 8;                                           \
        _Pragma("unroll")                                                      \
        for (int pi = 0; pi < 8; pi++) {                                       \
            int pos_ = pbase_ + pi;                                            \
            if (pos_ > POS_TOTAL-1) pos_ = POS_TOTAL-1;                        \
            const int y_ = pos_ / 255;                                         \
            const int x_ = pos_ - y_*255;                                      \
            const float* fp_ = featT + ((size_t)(y_*256 + x_))*256 + rm;       \
            patch[0][pi] = fp_[0];                                             \
            patch[1][pi] = fp_[256];                                           \
            patch[2][pi] = fp_[65536];                                         \
            patch[3][pi] = fp_[65536 + 256];                                   \
        }                                                                      \
    }

#define W_LOADS(DST, SG)                                                       \
    {                                                                          \
        const int fg_ = (SG) & 15;                                             \
        const int pbase_ = (pb0 + ((SG) >> 4)) * 8;                            \
        const int f_ = fg_*4 + fw;                                             \
        _Pragma("unroll")                                                      \
        for (int pi = 0; pi < 8; pi++) {                                       \
            int pos_ = pbase_ + pi;                                            \
            if (pos_ > POS_TOTAL-1) pos_ = POS_TOTAL-1;                        \
            DST[pi] = w1[(size_t)(f_*POS_TOTAL + pos_)*N1 + nb + rw];          \
        }                                                                      \
    }

#define STAGE(BUF, SG, WSRC)                                                   \
    {                                                                          \
        const int fg_ = (SG) & 15;                                             \
        const int pbase_ = (pb0 + ((SG) >> 4)) * 8;                            \
        _Pragma("unroll")                                                      \
        for (int j = 0; j < 2; j++) {                                          \
            const int f_ = fg_*4 + fh*2 + j;                                   \
            const float4 cc_ = *(const float4*)&cwL[f_*4];                     \
            const float cbv_ = cbL[f_];                                        \
            unsigned int apk_[4];                                              \
            _Pragma("unroll")                                                  \
            for (int pi = 0; pi < 8; pi++) {                                   \
                float v_ = patch[0][pi]*cc_.x + patch[1][pi]*cc_.y             \
                         + patch[2][pi]*cc_.z + patch[3][pi]*cc_.w + cbv_;     \
                v_ = (pbase_ + pi < POS_TOTAL) ? fmaxf(v_, 0.f) : 0.f;         \
                const unsigned short ab_ = f2bf_rne(v_);                       \
                if (pi & 1) apk_[pi>>1] |= (unsigned int)ab_ << 16;            \
                else        apk_[pi>>1]  = ab_;                                \
            }                                                                  \
            *(uint4*)&As[BUF][(((fh*2+j)*256) + rm)*8] = *(uint4*)&apk_[0];    \
        }                                                                      \
        unsigned int wpk_[4];                                                  \
        _Pragma("unroll")                                                      \
        for (int pi = 0; pi < 8; pi++) {                                       \
            const unsigned short wb_ = f2bf_rne(WSRC[pi]);                     \
            if (pi & 1) wpk_[pi>>1] |= (unsigned int)wb_ << 16;                \
            else        wpk_[pi>>1]  = wb_;                                    \
        }                                                                      \
        *(uint4*)&Ws[BUF][((fw*128) + rw)*8] = *(uint4*)&wpk_[0];              \
    }

#define DO_MFMA(BUF)                                                           \
    {                                                                          \
        bf16x8 af_[4], bf_[4];                                                 \
        _Pragma("unroll")                                                      \
        for (int mg = 0; mg < 4; mg++)                                         \
            af_[mg] = *(const bf16x8*)&As[BUF][((fq*256) + wm+mg*16+fr)*8];    \
        _Pragma("unroll")                                                      \
        for (int ng = 0; ng < 4; ng++)                                         \
            bf_[ng] = *(const bf16x8*)&Ws[BUF][((fq*128) + wn+ng*16+fr)*8];    \
        __builtin_amdgcn_s_setprio(1);                                         \
        _Pragma("unroll")                                                      \
        for (int mg = 0; mg < 4; mg++)                                         \
            _Pragma("unroll")                                                  \
            for (int ng = 0; ng < 4; ng++)                                     \
                acc[mg][ng] = __builtin_amdgcn_mfma_f32_16x16x32_bf16(         \
                    af_[mg], bf_[ng], acc[mg][ng], 0, 0, 0);                   \
        __builtin_amdgcn_s_setprio(0);                                         \
    }

    // prologue
    PATCH_LOADS(pb0);
    W_LOADS(wvA, 0);
    W_LOADS(wvB, 1);
    __syncthreads();            // cwL/cbL visible (full drain, once)
    STAGE(0, 0, wvA);
    LB();

    #pragma unroll 1
    for (int g = 0; g < 32; g++) {
        const int S = 2*g;
        if (g < 31) W_LOADS(wvA, S+2);
        DO_MFMA(0);
        STAGE(1, S+1, wvB);                          // vmcnt counted (wvA in flight)
        if (g < 31 && ((S+2) & 15) == 0) PATCH_LOADS(pb0 + ((S+2) >> 4));
        if (g < 31) W_LOADS(wvB, S+3);
        LB();
        DO_MFMA(1);
        if (g < 31) STAGE(0, S+2, wvA);              // vmcnt counted (wvB in flight)
        LB();
    }

    // ---- write fp32 partial tile ----
    float* pp = partial + (size_t)kt * (256*N1) + nb;
    #pragma unroll
    for (int mg = 0; mg < 4; mg++)
        #pragma unroll
        for (int ng = 0; ng < 4; ng++) {
            const int col = wn + ng*16 + fr;
            #pragma unroll
            for (int j = 0; j < 4; j++) {
                const int row = wm + mg*16 + fq*4 + j;
                pp[(size_t)row*N1 + col] = acc[mg][ng][j];
            }
        }
#undef PATCH_LOADS
#undef W_LOADS
#undef STAGE
#undef DO_MFMA
}

// ------- K3: reduce partials + b1/relu + h@w2 relu + @w3 + b3 -------
__global__ __launch_bounds__(256) void k_head(
    const float* __restrict__ partial, int KT_,
    const float* __restrict__ b1, const float* __restrict__ w2,
    const float* __restrict__ b2, const float* __restrict__ w3,
    const float* __restrict__ b3, float* __restrict__ out)
{
    __shared__ float h1s[256];
    __shared__ float h2s[32];
    const int b = blockIdx.x, t = threadIdx.x;

    float s = b1[t];
    for (int kt = 0; kt < KT_; kt++)
        s += partial[(size_t)kt*(256*N1) + (size_t)b*N1 + t];
    h1s[t] = fmaxf(s, 0.f);
    __syncthreads();

    if (t < 32) {
        float s2 = b2[t];
        for (int i = 0; i < 256; i++) s2 += h1s[i] * w2[i*32 + t];
        h2s[t] = fmaxf(s2, 0.f);
    }
    __syncthreads();

    if (t < 2) {
        float s3 = b3[t];
        #pragma unroll
        for (int i = 0; i < 32; i++) s3 += h2s[i] * w3[i*2 + t];
        out[b*2 + t] = s3;
    }
}

extern "C" void kernel_launch(void* const* d_in, const int* in_sizes, int n_in,
                              void* d_out, int out_size, void* d_ws, size_t ws_size,
                              hipStream_t stream) {
    const float* X    = (const float*)d_in[0];
    const float* attW = (const float*)d_in[1];
    const float* attU = (const float*)d_in[2];
    const float* attV = (const float*)d_in[3];
    const float* cw   = (const float*)d_in[4];
    const float* cb   = (const float*)d_in[5];
    const float* w1   = (const float*)d_in[6];
    const float* b1   = (const float*)d_in[7];
    const float* w2   = (const float*)d_in[8];
    const float* b2   = (const float*)d_in[9];
    const float* w3   = (const float*)d_in[10];
    const float* b3   = (const float*)d_in[11];
    float* out = (float*)d_out;

    float* featL   = (float*)d_ws;                                   //  8 MB
    float* featT   = (float*)((char*)d_ws + (8u<<20));               //  8 MB
    float* partial = (float*)((char*)d_ws + (16u<<20));              // 65 MB

    k_attn <<<dim3(B_),       dim3(256), 0, stream>>>(X, attW, attU, attV, featL);
    k_tr   <<<dim3(256, 8),   dim3(256), 0, stream>>>(featL, featT);
    k_gemm1<<<dim3(2, KT),    dim3(512), 0, stream>>>(featT, cw, cb, w1, partial);
    k_head <<<dim3(B_),       dim3(256), 0, stream>>>(partial, KT, b1, w2, b2, w3, b3, out);
}

// Round 7
// 350.371 us; speedup vs baseline: 1.1522x; 1.1522x over previous
//
#include <hip/hip_runtime.h>
#include <hip/hip_bf16.h>

#define B_ 256
#define T_ 32
#define F_ 128
#define H_ 128
#define NF 64
#define OH 31
#define OW 255
#define POS_TOTAL (OH*OW)      // 7905
#define N1 256
#define KT 496                 // K-slice blocks (16 pos each)
#define NSTEPS 32              // steps of K=32 (4 filters x 8 pos)

typedef __attribute__((ext_vector_type(8))) short bf16x8;
typedef __attribute__((ext_vector_type(4))) float f32x4;

__device__ __forceinline__ unsigned int cvtpk(float lo, float hi) {
    unsigned int r;
    asm("v_cvt_pk_bf16_f32 %0, %1, %2" : "=v"(r) : "v"(lo), "v"(hi));
    return r;
}

// raw barrier: drain LDS ops only; vmem loads stay in flight (T4)
#define LB() do { asm volatile("s_waitcnt lgkmcnt(0)" ::: "memory"); \
                  __builtin_amdgcn_s_barrier(); } while (0)

// ---------------- K1: attention -> featL [b=256][rc=8192] ----------------
__global__ __launch_bounds__(256) void k_attn(
    const float* __restrict__ X, const float* __restrict__ W,
    const float* __restrict__ U, const float* __restrict__ V,
    float* __restrict__ featL)
{
    __shared__ float Xs[T_][F_];
    __shared__ float xw[T_][H_];
    __shared__ float xu[T_][H_];
    __shared__ float sc[T_][T_];
    __shared__ float Vs[H_];

    const int b = blockIdx.x;
    const int t = threadIdx.x;
    const float* Xb = X + (size_t)b * T_ * F_;

    for (int idx = t; idx < T_*F_; idx += 256) ((float*)Xs)[idx] = Xb[idx];
    if (t < H_) Vs[t] = V[t];
    __syncthreads();

    {
        const int h = t & 127, half = t >> 7;
        float aw[16], au[16];
        #pragma unroll
        for (int r = 0; r < 16; r++) { aw[r] = 0.f; au[r] = 0.f; }
        for (int f = 0; f < F_; f++) {
            const float wv = W[f*H_ + h];
            const float uv = U[f*H_ + h];
            #pragma unroll
            for (int r = 0; r < 16; r++) {
                const float xv = Xs[half*16 + r][f];
                aw[r] += xv * wv;
                au[r] += xv * uv;
            }
        }
        #pragma unroll
        for (int r = 0; r < 16; r++) {
            xw[half*16 + r][h] = aw[r];
            xu[half*16 + r][h] = au[r];
        }
    }
    __syncthreads();

    {
        const int i = t >> 3;
        const int j0 = (t & 7) * 4;
        float s0 = 0.f, s1 = 0.f, s2 = 0.f, s3 = 0.f;
        for (int h = 0; h < H_; h++) {
            const float xwv = xw[i][h];
            const float vv  = Vs[h];
            s0 += tanhf(xwv + xu[j0+0][h]) * vv;
            s1 += tanhf(xwv + xu[j0+1][h]) * vv;
            s2 += tanhf(xwv + xu[j0+2][h]) * vv;
            s3 += tanhf(xwv + xu[j0+3][h]) * vv;
        }
        sc[i][j0+0] = s0; sc[i][j0+1] = s1; sc[i][j0+2] = s2; sc[i][j0+3] = s3;
    }
    __syncthreads();

    if (t < T_) {
        float m = -1e30f;
        #pragma unroll
        for (int j = 0; j < T_; j++) m = fmaxf(m, sc[t][j]);
        float sum = 0.f;
        #pragma unroll
        for (int j = 0; j < T_; j++) sum += expf(sc[t][j] - m);
        const float inv = 1.f / sum;
        #pragma unroll
        for (int j = 0; j < T_; j++) {
            const float a = expf(sc[t][j] - m) * inv;
            sc[t][j] = (j == t) ? 0.f : a;
        }
    }
    __syncthreads();

    for (int idx = t; idx < T_*F_; idx += 256) {
        const int row = idx >> 7, f = idx & 127;
        float acc = 0.f;
        #pragma unroll
        for (int j = 0; j < T_; j++) acc += sc[row][j] * Xs[j][f];
        float* fr = featL + (size_t)b*8192 + row*256;
        fr[f]       = Xs[row][f];
        fr[128 + f] = acc;
    }
}

// -------- K1b: transpose featL[b][rc] -> featT[rc][b], LDS-tiled --------
__global__ __launch_bounds__(256) void k_tr(
    const float* __restrict__ src, float* __restrict__ dst)
{
    __shared__ float tile[32][33];
    const int rc0 = blockIdx.x * 32;
    const int b0  = blockIdx.y * 32;
    const int tx = threadIdx.x & 31;
    const int ty = threadIdx.x >> 5;
    #pragma unroll
    for (int r = 0; r < 32; r += 8)
        tile[ty + r][tx] = src[(size_t)(b0 + ty + r)*8192 + rc0 + tx];
    __syncthreads();
    #pragma unroll
    for (int r = 0; r < 32; r += 8)
        dst[(size_t)(rc0 + ty + r)*256 + b0 + tx] = tile[tx][ty + r];
}

// ------- K2: fused conv + MFMA GEMM1, 1-iteration-slack pipeline -------
// Grid 496. Tile 256x256, K-slice = 16 pos, 32 steps of K=32 (4f x 8pos).
__global__ __launch_bounds__(512, 2) void k_gemm1(
    const float* __restrict__ featT, const float* __restrict__ cw,
    const float* __restrict__ cb, const float* __restrict__ w1,
    float* __restrict__ partial)
{
    __shared__ unsigned short As[2][4*256*8];   // 2 x 16 KiB [blk][m][8k]
    __shared__ unsigned short Ws[2][4*256*8];   // 2 x 16 KiB [blk][n][8k]
    __shared__ float cwL[256];
    __shared__ float cbL[64];

    const int t  = threadIdx.x;
    const int kt = blockIdx.x;

    if (t < 256) cwL[t] = cw[t];
    if (t < 64)  cbL[t] = cb[t];

    const int rm = t & 255;      // A row (batch) == W col (n)
    const int fh = t >> 8;       // 0/1: filter-half for both staging roles

    // MFMA role: 8 waves = 2(m) x 4(n); wave tile 128x64
    const int lane = t & 63, wid = t >> 6;
    const int wm = (wid >> 2) * 128;
    const int wn = (wid & 3) * 64;
    const int fr = lane & 15, fq = lane >> 4;

    f32x4 acc[8][4];
    #pragma unroll
    for (int i = 0; i < 8; i++)
        #pragma unroll
        for (int j = 0; j < 4; j++)
            acc[i][j] = (f32x4){0.f, 0.f, 0.f, 0.f};

    float patch[4][8];           // 4 taps x 8 pos for row rm
    float wvA[2][8], wvB[2][8];  // two pipelined w1 sets: [filter j][pos]

    const int pb0 = kt * 2;      // pos-block base (8 pos each), 2 per block

#define PATCH_LOADS(PB)                                                        \
    {                                                                          \
        const int pbase_ = (PB) * 8;                                           \
        _Pragma("unroll")                                                      \
        for (int pi = 0; pi < 8; pi++) {                                       \
            int pos_ = pbase_ + pi;                                            \
            if (pos_ > POS_TOTAL-1) pos_ = POS_TOTAL-1;                        \
            const int y_ = pos_ / 255;                                         \
            const int x_ = pos_ - y_*255;                                      \
            const float* fp_ = featT + ((size_t)(y_*256 + x_))*256 + rm;       \
            patch[0][pi] = fp_[0];                                             \
            patch[1][pi] = fp_[256];                                           \
            patch[2][pi] = fp_[65536];                                         \
            patch[3][pi] = fp_[65536 + 256];                                   \
        }                                                                      \
    }

#define W_LOADS(DST, SG)                                                       \
    {                                                                          \
        const int fg_ = (SG) & 15;                                             \
        const int pbase_ = (pb0 + ((SG) >> 4)) * 8;                            \
        _Pragma("unroll")                                                      \
        for (int j = 0; j < 2; j++) {                                          \
            const int f_ = fg_*4 + fh*2 + j;                                   \
            _Pragma("unroll")                                                  \
            for (int pi = 0; pi < 8; pi++) {                                   \
                int pos_ = pbase_ + pi;                                        \
                if (pos_ > POS_TOTAL-1) pos_ = POS_TOTAL-1;                    \
                DST[j][pi] = w1[(size_t)(f_*POS_TOTAL + pos_)*N1 + rm];        \
            }                                                                  \
        }                                                                      \
    }

#define STAGE(BUF, SG, WSRC)                                                   \
    {                                                                          \
        const int fg_ = (SG) & 15;                                             \
        const int pbase_ = (pb0 + ((SG) >> 4)) * 8;                            \
        _Pragma("unroll")                                                      \
        for (int j = 0; j < 2; j++) {                                          \
            const int f_ = fg_*4 + fh*2 + j;                                   \
            const float4 cc_ = *(const float4*)&cwL[f_*4];                     \
            const float cbv_ = cbL[f_];                                        \
            float cv_[8];                                                      \
            _Pragma("unroll")                                                  \
            for (int pi = 0; pi < 8; pi++) {                                   \
                float v_ = patch[0][pi]*cc_.x + patch[1][pi]*cc_.y             \
                         + patch[2][pi]*cc_.z + patch[3][pi]*cc_.w + cbv_;     \
                cv_[pi] = (pbase_ + pi < POS_TOTAL) ? fmaxf(v_, 0.f) : 0.f;    \
            }                                                                  \
            unsigned int apk_[4], wpk_[4];                                     \
            _Pragma("unroll")                                                  \
            for (int pi = 0; pi < 4; pi++) {                                   \
                apk_[pi] = cvtpk(cv_[2*pi], cv_[2*pi+1]);                      \
                wpk_[pi] = cvtpk(WSRC[j][2*pi], WSRC[j][2*pi+1]);              \
            }                                                                  \
            *(uint4*)&As[BUF][(((fh*2+j)*256) + rm)*8] = *(uint4*)&apk_[0];    \
            *(uint4*)&Ws[BUF][(((fh*2+j)*256) + rm)*8] = *(uint4*)&wpk_[0];    \
        }                                                                      \
    }

#define DO_MFMA(BUF)                                                           \
    {                                                                          \
        bf16x8 af_[8], bf_[4];                                                 \
        _Pragma("unroll")                                                      \
        for (int mg = 0; mg < 8; mg++)                                         \
            af_[mg] = *(const bf16x8*)&As[BUF][((fq*256) + wm+mg*16+fr)*8];    \
        _Pragma("unroll")                                                      \
        for (int ng = 0; ng < 4; ng++)                                         \
            bf_[ng] = *(const bf16x8*)&Ws[BUF][((fq*256) + wn+ng*16+fr)*8];    \
        __builtin_amdgcn_s_setprio(1);                                         \
        _Pragma("unroll")                                                      \
        for (int mg = 0; mg < 8; mg++)                                         \
            _Pragma("unroll")                                                  \
            for (int ng = 0; ng < 4; ng++)                                     \
                acc[mg][ng] = __builtin_amdgcn_mfma_f32_16x16x32_bf16(         \
                    af_[mg], bf_[ng], acc[mg][ng], 0, 0, 0);                   \
        __builtin_amdgcn_s_setprio(0);                                         \
    }

    // ---- prologue ----
    PATCH_LOADS(pb0);
    W_LOADS(wvA, 0);
    W_LOADS(wvB, 1);
    __syncthreads();             // cwL/cbL visible (full drain, once)
    STAGE(0, 0, wvA);
    W_LOADS(wvA, 2);
    LB();

    // ---- steady state: 2 steps per iter, every wv set has >=1 iter slack ----
    #pragma unroll 1
    for (int g = 0; g < 15; g++) {
        const int S = 2*g;
        DO_MFMA(0);                                  // step S
        STAGE(1, S+1, wvB);                          // wvB(S+1): 1-iter-old ✓
        if (S+3 < NSTEPS) W_LOADS(wvB, S+3);
        LB();
        DO_MFMA(1);                                  // step S+1
        if (g == 7) PATCH_LOADS(pb0 + 1);            // posblock crossing (step 16)
        STAGE(0, S+2, wvA);                          // wvA(S+2): 1-iter-old ✓
        if (S+4 < NSTEPS) W_LOADS(wvA, S+4);
        LB();
    }
    // ---- epilogue: steps 30, 31 ----
    DO_MFMA(0);
    STAGE(1, 31, wvB);
    LB();
    DO_MFMA(1);

    // ---- write fp32 partial tile ----
    float* pp = partial + (size_t)kt * (256*N1);
    #pragma unroll
    for (int mg = 0; mg < 8; mg++)
        #pragma unroll
        for (int ng = 0; ng < 4; ng++) {
            const int col = wn + ng*16 + fr;
            #pragma unroll
            for (int j = 0; j < 4; j++) {
                const int row = wm + mg*16 + fq*4 + j;
                pp[(size_t)row*N1 + col] = acc[mg][ng][j];
            }
        }
#undef PATCH_LOADS
#undef W_LOADS
#undef STAGE
#undef DO_MFMA
}

// ------- K3: reduce partials + b1/relu + h@w2 relu + @w3 + b3 -------
__global__ __launch_bounds__(256) void k_head(
    const float* __restrict__ partial,
    const float* __restrict__ b1, const float* __restrict__ w2,
    const float* __restrict__ b2, const float* __restrict__ w3,
    const float* __restrict__ b3, float* __restrict__ out)
{
    __shared__ float h1s[256];
    __shared__ float h2s[32];
    const int b = blockIdx.x, t = threadIdx.x;

    const float* pb = partial + (size_t)b*N1 + t;
    float s0 = 0.f, s1 = 0.f, s2 = 0.f, s3 = 0.f;
    #pragma unroll 2
    for (int kt = 0; kt < KT; kt += 4) {
        s0 += pb[(size_t)(kt+0)*65536];
        s1 += pb[(size_t)(kt+1)*65536];
        s2 += pb[(size_t)(kt+2)*65536];
        s3 += pb[(size_t)(kt+3)*65536];
    }
    h1s[t] = fmaxf(b1[t] + ((s0+s1)+(s2+s3)), 0.f);
    __syncthreads();

    if (t < 32) {
        float s2v = b2[t];
        for (int i = 0; i < 256; i++) s2v += h1s[i] * w2[i*32 + t];
        h2s[t] = fmaxf(s2v, 0.f);
    }
    __syncthreads();

    if (t < 2) {
        float s3v = b3[t];
        #pragma unroll
        for (int i = 0; i < 32; i++) s3v += h2s[i] * w3[i*2 + t];
        out[b*2 + t] = s3v;
    }
}

extern "C" void kernel_launch(void* const* d_in, const int* in_sizes, int n_in,
                              void* d_out, int out_size, void* d_ws, size_t ws_size,
                              hipStream_t stream) {
    const float* X    = (const float*)d_in[0];
    const float* attW = (const float*)d_in[1];
    const float* attU = (const float*)d_in[2];
    const float* attV = (const float*)d_in[3];
    const float* cw   = (const float*)d_in[4];
    const float* cb   = (const float*)d_in[5];
    const float* w1   = (const float*)d_in[6];
    const float* b1   = (const float*)d_in[7];
    const float* w2   = (const float*)d_in[8];
    const float* b2   = (const float*)d_in[9];
    const float* w3   = (const float*)d_in[10];
    const float* b3   = (const float*)d_in[11];
    float* out = (float*)d_out;

    float* featL   = (float*)d_ws;                                   //  8 MB
    float* featT   = (float*)((char*)d_ws + (8u<<20));               //  8 MB
    float* partial = (float*)((char*)d_ws + (16u<<20));              // 130 MB

    k_attn <<<dim3(B_),       dim3(256), 0, stream>>>(X, attW, attU, attV, featL);
    k_tr   <<<dim3(256, 8),   dim3(256), 0, stream>>>(featL, featT);
    k_gemm1<<<dim3(KT),       dim3(512), 0, stream>>>(featT, cw, cb, w1, partial);
    k_head <<<dim3(B_),       dim3(256), 0, stream>>>(partial, b1, w2, b2, w3, b3, out);
}

// Round 9
// 309.711 us; speedup vs baseline: 1.3034x; 1.1313x over previous
//
#include <hip/hip_runtime.h>
#include <hip/hip_bf16.h>

#define B_ 256
#define T_ 32
#define F_ 128
#define H_ 128
#define NF 64
#define OH 31
#define OW 255
#define POS_TOTAL (OH*OW)      // 7905
#define N1 256
#define KT 248                 // kt blocks; each owns 32 consecutive pos, all 64 filters

typedef __attribute__((ext_vector_type(8))) short bf16x8;
typedef __attribute__((ext_vector_type(4))) float f32x4;

__device__ __forceinline__ unsigned int cvtpk(float lo, float hi) {
    unsigned int r;
    asm("v_cvt_pk_bf16_f32 %0, %1, %2" : "=v"(r) : "v"(lo), "v"(hi));
    return r;
}

__device__ __forceinline__ void gll16(const void* g, void* l) {
    __builtin_amdgcn_global_load_lds(
        (const __attribute__((address_space(1))) void*)g,
        (__attribute__((address_space(3))) void*)l, 16, 0, 0);
}

// ---------------- K1: attention -> featL [b=256][rc=8192] ----------------
__global__ __launch_bounds__(256) void k_attn(
    const float* __restrict__ X, const float* __restrict__ W,
    const float* __restrict__ U, const float* __restrict__ V,
    float* __restrict__ featL)
{
    __shared__ float Xs[T_][F_];
    __shared__ float xw[T_][H_];
    __shared__ float xu[T_][H_];
    __shared__ float sc[T_][T_];
    __shared__ float Vs[H_];

    const int b = blockIdx.x;
    const int t = threadIdx.x;
    const float* Xb = X + (size_t)b * T_ * F_;

    for (int idx = t; idx < T_*F_; idx += 256) ((float*)Xs)[idx] = Xb[idx];
    if (t < H_) Vs[t] = V[t];
    __syncthreads();

    {
        const int h = t & 127, half = t >> 7;
        float aw[16], au[16];
        #pragma unroll
        for (int r = 0; r < 16; r++) { aw[r] = 0.f; au[r] = 0.f; }
        for (int f = 0; f < F_; f++) {
            const float wv = W[f*H_ + h];
            const float uv = U[f*H_ + h];
            #pragma unroll
            for (int r = 0; r < 16; r++) {
                const float xv = Xs[half*16 + r][f];
                aw[r] += xv * wv;
                au[r] += xv * uv;
            }
        }
        #pragma unroll
        for (int r = 0; r < 16; r++) {
            xw[half*16 + r][h] = aw[r];
            xu[half*16 + r][h] = au[r];
        }
    }
    __syncthreads();

    {
        const int i = t >> 3;
        const int j0 = (t & 7) * 4;
        float s0 = 0.f, s1 = 0.f, s2 = 0.f, s3 = 0.f;
        for (int h = 0; h < H_; h++) {
            const float xwv = xw[i][h];
            const float vv  = Vs[h];
            s0 += tanhf(xwv + xu[j0+0][h]) * vv;
            s1 += tanhf(xwv + xu[j0+1][h]) * vv;
            s2 += tanhf(xwv + xu[j0+2][h]) * vv;
            s3 += tanhf(xwv + xu[j0+3][h]) * vv;
        }
        sc[i][j0+0] = s0; sc[i][j0+1] = s1; sc[i][j0+2] = s2; sc[i][j0+3] = s3;
    }
    __syncthreads();

    if (t < T_) {
        float m = -1e30f;
        #pragma unroll
        for (int j = 0; j < T_; j++) m = fmaxf(m, sc[t][j]);
        float sum = 0.f;
        #pragma unroll
        for (int j = 0; j < T_; j++) sum += expf(sc[t][j] - m);
        const float inv = 1.f / sum;
        #pragma unroll
        for (int j = 0; j < T_; j++) {
            const float a = expf(sc[t][j] - m) * inv;
            sc[t][j] = (j == t) ? 0.f : a;
        }
    }
    __syncthreads();

    for (int idx = t; idx < T_*F_; idx += 256) {
        const int row = idx >> 7, f = idx & 127;
        float acc = 0.f;
        #pragma unroll
        for (int j = 0; j < T_; j++) acc += sc[row][j] * Xs[j][f];
        float* fr = featL + (size_t)b*8192 + row*256;
        fr[f]       = Xs[row][f];
        fr[128 + f] = acc;
    }
}

// -------- K1b: transpose featL[b][rc] -> featT[rc][b], LDS-tiled --------
__global__ __launch_bounds__(256) void k_tr(
    const float* __restrict__ src, float* __restrict__ dst)
{
    __shared__ float tile[32][33];
    const int rc0 = blockIdx.x * 32;
    const int b0  = blockIdx.y * 32;
    const int tx = threadIdx.x & 31;
    const int ty = threadIdx.x >> 5;
    #pragma unroll
    for (int r = 0; r < 32; r += 8)
        tile[ty + r][tx] = src[(size_t)(b0 + ty + r)*8192 + rc0 + tx];
    __syncthreads();
    #pragma unroll
    for (int r = 0; r < 32; r += 8)
        dst[(size_t)(rc0 + ty + r)*256 + b0 + tx] = tile[tx][ty + r];
}

// ------- K2: fused conv + MFMA GEMM1, global_load_lds w1 stream -------
// Grid (2 nt, 248 kt). Tile 256m x 128n; K-step = 1 filter x 32 consecutive pos.
// w1 per step = 32 rows x 512B (this nt's half) DMA'd f32 to LDS (3 bufs),
// per-lane source addresses (2 rows per gll16). Patch is block-constant.
__global__ __launch_bounds__(512, 2) void k_gemm1(
    const float* __restrict__ featT, const float* __restrict__ cw,
    const float* __restrict__ cb, const float* __restrict__ w1,
    float* __restrict__ partial)
{
    __shared__ float          WsL[3][16][260];   // ~49 KiB: [buf][rowpair][2*128+4]
    __shared__ unsigned short As[2][256][40];    // 40 KiB: [buf][m][k] pitch 40
    __shared__ float cwL[256];
    __shared__ float cbL[64];

    const int t  = threadIdx.x;
    const int nt = blockIdx.x;         // 0/1 n-half
    const int kt = blockIdx.y;         // 0..247
    const int nb = nt * 128;
    const int pos0 = kt * 32;

    if (t < 256) cwL[t] = cw[t];
    if (t < 64)  cbL[t] = cb[t];

    const int rm = t & 255;      // A row (batch)
    const int ph = t >> 8;       // 0/1: pos half (16 pos each)
    const int pbase = pos0 + ph*16;

    // MFMA role: 8 waves = 4(m) x 2(n); wave tile 64x64
    const int lane = t & 63, wid = t >> 6;
    const int wm = (wid & 3) * 64;
    const int wn = (wid >> 2) * 64;
    const int fr = lane & 15, fq = lane >> 4;

    f32x4 acc[4][4];
    #pragma unroll
    for (int i = 0; i < 4; i++)
        #pragma unroll
        for (int j = 0; j < 4; j++)
            acc[i][j] = (f32x4){0.f, 0.f, 0.f, 0.f};

    // ---- block-constant conv patch: 4 taps x 16 pos per thread ----
    float p0[16], p1[16], p2[16], p3[16];
    #pragma unroll
    for (int i = 0; i < 16; i++) {
        int p = pbase + i; if (p > POS_TOTAL-1) p = POS_TOTAL-1;
        const int y = p / 255, x = p - y*255;
        const float* fp = featT + ((size_t)(y*256 + x))*256 + rm;
        p0[i] = fp[0];
        p1[i] = fp[256];
        p2[i] = fp[65536];
        p3[i] = fp[65536 + 256];
    }

    // w1 DMA: wave wid covers row-pairs wid*2, wid*2+1 (4 rows). Per-lane src!
#define GLLW(F2)                                                               \
    {                                                                          \
        const int wb_ = (F2) % 3;                                              \
        _Pragma("unroll")                                                      \
        for (int j = 0; j < 2; j++) {                                          \
            const int pr_ = wid*2 + j;               /* pair 0..15 */          \
            int pos_ = pos0 + pr_*2 + (lane >> 5);                             \
            if (pos_ > POS_TOTAL-1) pos_ = POS_TOTAL-1;                        \
            gll16(w1 + ((size_t)(F2)*POS_TOTAL + pos_)*N1 + nb                 \
                     + ((lane & 31) << 2),                                     \
                  &WsL[wb_][pr_][0]);                                          \
        }                                                                      \
    }

    // conv + bf16 + ds_write: thread covers row rm, pos half ph, filter F2
#define CONVW(F2)                                                              \
    {                                                                          \
        const float4 cc_ = *(const float4*)&cwL[(F2)*4];                       \
        const float cbv_ = cbL[F2];                                            \
        unsigned int pk_[8];                                                   \
        _Pragma("unroll")                                                      \
        for (int i2 = 0; i2 < 8; i2++) {                                       \
            float v0_ = p0[2*i2]*cc_.x + p1[2*i2]*cc_.y                        \
                      + p2[2*i2]*cc_.z + p3[2*i2]*cc_.w + cbv_;                \
            float v1_ = p0[2*i2+1]*cc_.x + p1[2*i2+1]*cc_.y                    \
                      + p2[2*i2+1]*cc_.z + p3[2*i2+1]*cc_.w + cbv_;            \
            v0_ = (pbase + 2*i2     < POS_TOTAL) ? fmaxf(v0_, 0.f) : 0.f;      \
            v1_ = (pbase + 2*i2 + 1 < POS_TOTAL) ? fmaxf(v1_, 0.f) : 0.f;      \
            pk_[i2] = cvtpk(v0_, v1_);                                         \
        }                                                                      \
        *(uint4*)&As[(F2) & 1][rm][ph*16    ] = *(uint4*)&pk_[0];              \
        *(uint4*)&As[(F2) & 1][rm][ph*16 + 8] = *(uint4*)&pk_[4];              \
    }

    // ---- prologue ----
    GLLW(0);
    GLLW(1);
    __syncthreads();           // full drain once: cwL/patch/Ws0/Ws1 all ready
    CONVW(0);
    CONVW(1);
    asm volatile("s_waitcnt lgkmcnt(0)" ::: "memory");
    __builtin_amdgcn_s_barrier();

    #pragma unroll 1
    for (int f = 0; f < 64; f++) {
        const int cur = f & 1;
        const int wb  = f % 3;

        // ---- part A: A-fragments -> regs, then As[cur] is free ----
        bf16x8 af_[4];
        #pragma unroll
        for (int mg = 0; mg < 4; mg++)
            af_[mg] = *(const bf16x8*)&As[cur][wm + mg*16 + fr][fq*8];
        asm volatile("s_waitcnt lgkmcnt(0)" ::: "memory");
        __builtin_amdgcn_s_barrier();                     // bar A

        // ---- part B: restage (f+2) while MFMA(f) runs ----
        if (f < 62) {
            GLLW(f + 2);
            CONVW(f + 2);
        }

        {
            __builtin_amdgcn_s_setprio(1);
            #pragma unroll
            for (int ng = 0; ng < 4; ng++) {
                const int colb = wn + ng*16 + fr;
                float w_[8];
                #pragma unroll
                for (int j = 0; j < 8; j++)
                    w_[j] = WsL[wb][fq*4 + (j >> 1)][(j & 1)*128 + colb];
                bf16x8 bfr;
                unsigned int* bu = (unsigned int*)&bfr;
                #pragma unroll
                for (int j2 = 0; j2 < 4; j2++)
                    bu[j2] = cvtpk(w_[2*j2], w_[2*j2+1]);
                #pragma unroll
                for (int mg = 0; mg < 4; mg++)
                    acc[mg][ng] = __builtin_amdgcn_mfma_f32_16x16x32_bf16(
                        af_[mg], bfr, acc[mg][ng], 0, 0, 0);
            }
            __builtin_amdgcn_s_setprio(0);
        }

        if (f < 62) {
            asm volatile("s_waitcnt vmcnt(2) lgkmcnt(0)" ::: "memory");
        } else {
            asm volatile("s_waitcnt vmcnt(0) lgkmcnt(0)" ::: "memory");
        }
        __builtin_amdgcn_s_barrier();                     // bar B
    }

    // ---- write fp32 partial tile ----
    float* pp = partial + (size_t)kt * (256*N1) + nb;
    #pragma unroll
    for (int mg = 0; mg < 4; mg++)
        #pragma unroll
        for (int ng = 0; ng < 4; ng++) {
            const int col = wn + ng*16 + fr;
            #pragma unroll
            for (int j = 0; j < 4; j++) {
                const int row = wm + mg*16 + fq*4 + j;
                pp[(size_t)row*N1 + col] = acc[mg][ng][j];
            }
        }
#undef GLLW
#undef CONVW
}

// ------- K3: reduce partials + b1/relu + h@w2 relu + @w3 + b3 -------
__global__ __launch_bounds__(256) void k_head(
    const float* __restrict__ partial,
    const float* __restrict__ b1, const float* __restrict__ w2,
    const float* __restrict__ b2, const float* __restrict__ w3,
    const float* __restrict__ b3, float* __restrict__ out)
{
    __shared__ float h1s[256];
    __shared__ float h2s[32];
    const int b = blockIdx.x, t = threadIdx.x;

    const float* pb = partial + (size_t)b*N1 + t;
    float s0 = 0.f, s1 = 0.f, s2 = 0.f, s3 = 0.f;
    #pragma unroll 2
    for (int kt = 0; kt < KT; kt += 4) {
        s0 += pb[(size_t)(kt+0)*65536];
        s1 += pb[(size_t)(kt+1)*65536];
        s2 += pb[(size_t)(kt+2)*65536];
        s3 += pb[(size_t)(kt+3)*65536];
    }
    h1s[t] = fmaxf(b1[t] + ((s0+s1)+(s2+s3)), 0.f);
    __syncthreads();

    if (t < 32) {
        float s2v = b2[t];
        for (int i = 0; i < 256; i++) s2v += h1s[i] * w2[i*32 + t];
        h2s[t] = fmaxf(s2v, 0.f);
    }
    __syncthreads();

    if (t < 2) {
        float s3v = b3[t];
        #pragma unroll
        for (int i = 0; i < 32; i++) s3v += h2s[i] * w3[i*2 + t];
        out[b*2 + t] = s3v;
    }
}

extern "C" void kernel_launch(void* const* d_in, const int* in_sizes, int n_in,
                              void* d_out, int out_size, void* d_ws, size_t ws_size,
                              hipStream_t stream) {
    const float* X    = (const float*)d_in[0];
    const float* attW = (const float*)d_in[1];
    const float* attU = (const float*)d_in[2];
    const float* attV = (const float*)d_in[3];
    const float* cw   = (const float*)d_in[4];
    const float* cb   = (const float*)d_in[5];
    const float* w1   = (const float*)d_in[6];
    const float* b1   = (const float*)d_in[7];
    const float* w2   = (const float*)d_in[8];
    const float* b2   = (const float*)d_in[9];
    const float* w3   = (const float*)d_in[10];
    const float* b3   = (const float*)d_in[11];
    float* out = (float*)d_out;

    float* featL   = (float*)d_ws;                                   //  8 MB
    float* featT   = (float*)((char*)d_ws + (8u<<20));               //  8 MB
    float* partial = (float*)((char*)d_ws + (16u<<20));              // 62 MB

    k_attn <<<dim3(B_),       dim3(256), 0, stream>>>(X, attW, attU, attV, featL);
    k_tr   <<<dim3(256, 8),   dim3(256), 0, stream>>>(featL, featT);
    k_gemm1<<<dim3(2, KT),    dim3(512), 0, stream>>>(featT, cw, cb, w1, partial);
    k_head <<<dim3(B_),       dim3(256), 0, stream>>>(partial, b1, w2, b2, w3, b3, out);
}